// Round 11
// baseline (367.116 us; speedup 1.0000x reference)
//
#include <hip/hip_runtime.h>

// 2-layer GCN, CSR-gather, bf16 payloads.
//   hist(atomic bucket totals) -> bscan(1 block) -> [scatter ∥ gemm, 1:1]
//   -> sort -> gather1 -> gather2f (gather + W2 matmul + pooling, fused).
// Kept: 1:1 scatter/gemm interleave (R9), 512-node buckets, packed 1-int
// bucket entries, bf16 payloads (R10), fused final (R10), sorted coalesced
// bucket writes (R12), uint4 gathers (R13), K-split coalesced gemm loads
// (R16), 2-node/thread gemm (R17/R20), predicated gather loads (R19),
// 32-edge rounds (R20), pair-pipelined gathers (R21).
// R18: global-atomic CSR REFUTED (random 4B stores).  R19: request cut
// NEUTRAL.  R21: gather ILP NEUTRAL -> gathers are service-rate-bound.
// R22: the 305K-element two-level scan machinery replaced by atomic
//   two-level allocation.  Within-bucket order is irrelevant (sort
//   re-sorts per node), so per-(bucket,block) bases can be atomicAdd
//   allocations: hist -> ~391 atomics/block onto 64B-padded bucket
//   totals; ONE small bscan block builds bstart+cursors; scatter gets
//   its base per nonempty bucket via one atomicAdd (drops 1.6M scattered
//   cbase loads + the counts array + scan1/scan2 dispatches).  CHUNK
//   4096 -> 8192 halves per-block fixed costs.

#define TPB 256
#define CHUNK 8192          // edges per scatter/hist block
#define BK_SHIFT 9
#define NPB 512             // nodes per bucket = 1 << BK_SHIFT
#define W1S 20              // w1s k-row stride in floats (bank-spread pad)
#define CPAD 16             // cursor/btot stride in ints (64B anti-serialize)

__device__ __forceinline__ float bf2f(unsigned short u) {
    union { unsigned int i; float f; } v; v.i = ((unsigned int)u) << 16; return v.f;
}
__device__ __forceinline__ unsigned short f2bf(float f) {
    union { float f; unsigned int i; } v; v.f = f;
    unsigned int r = v.i + 0x7fff + ((v.i >> 16) & 1);   // RNE
    return (unsigned short)(r >> 16);
}
// accumulate 8 bf16 (one uint4) into a[0..7]
__device__ __forceinline__ void bfacc8(uint4 v, float* a) {
    union { unsigned int i; float f; } lo, hi;
    lo.i = v.x << 16; hi.i = v.x & 0xffff0000u; a[0] += lo.f; a[1] += hi.f;
    lo.i = v.y << 16; hi.i = v.y & 0xffff0000u; a[2] += lo.f; a[3] += hi.f;
    lo.i = v.z << 16; hi.i = v.z & 0xffff0000u; a[4] += lo.f; a[5] += hi.f;
    lo.i = v.w << 16; hi.i = v.w & 0xffff0000u; a[6] += lo.f; a[7] += hi.f;
}
__device__ __forceinline__ void bfunp8(uint4 v, float* a) {
    union { unsigned int i; float f; } lo, hi;
    lo.i = v.x << 16; hi.i = v.x & 0xffff0000u; a[0] = lo.f; a[1] = hi.f;
    lo.i = v.y << 16; hi.i = v.y & 0xffff0000u; a[2] = lo.f; a[3] = hi.f;
    lo.i = v.z << 16; hi.i = v.z & 0xffff0000u; a[4] = lo.f; a[5] = hi.f;
    lo.i = v.w << 16; hi.i = v.w & 0xffff0000u; a[6] = lo.f; a[7] = hi.f;
}

// single-node 32-edge round (tail path), predicated uint4 loads (R19/R20)
__device__ __forceinline__ void gather32(const int* __restrict__ csr,
                                         const unsigned short* __restrict__ feat,
                                         int p, int p1, int l, int half, int sub,
                                         float* a) {
    int s_lo = csr[min(p + l, p1 - 1)];
    int s_hi = csr[min(p + 16 + l, p1 - 1)];
    int rem = p1 - p;
    int e0 = sub, e1 = 8 + sub, e2 = 16 + sub, e3 = 24 + sub;
    int src0 = __shfl(s_lo, e0, 16);
    int src1 = __shfl(s_lo, e1, 16);
    int src2 = __shfl(s_hi, e0, 16);
    int src3 = __shfl(s_hi, e1, 16);
    uint4 u0 = make_uint4(0, 0, 0, 0), u1 = make_uint4(0, 0, 0, 0);
    uint4 u2 = make_uint4(0, 0, 0, 0), u3 = make_uint4(0, 0, 0, 0);
    if (e0 < rem) u0 = *(const uint4*)&feat[(size_t)src0 * 16 + 8 * half];
    if (e1 < rem) u1 = *(const uint4*)&feat[(size_t)src1 * 16 + 8 * half];
    if (e2 < rem) u2 = *(const uint4*)&feat[(size_t)src2 * 16 + 8 * half];
    if (e3 < rem) u3 = *(const uint4*)&feat[(size_t)src3 * 16 + 8 * half];
    bfacc8(u0, a);
    bfacc8(u1, a);
    bfacc8(u2, a);
    bfacc8(u3, a);
}

// paired 32-edge round for two nodes: 4 csr loads + 8 predicated feat
// loads all issued before any accumulate (R21 in-flight depth 2x).
__device__ __forceinline__ void gather32_pair(const int* __restrict__ csr,
                                              const unsigned short* __restrict__ feat,
                                              int pA, int pA1, int pB, int pB1,
                                              int l, int half, int sub,
                                              float* a, float* b) {
    int sAlo = csr[min(pA + l, pA1 - 1)];
    int sAhi = csr[min(pA + 16 + l, pA1 - 1)];
    int sBlo = csr[min(pB + l, pB1 - 1)];
    int sBhi = csr[min(pB + 16 + l, pB1 - 1)];
    int remA = pA1 - pA, remB = pB1 - pB;
    int e0 = sub, e1 = 8 + sub, e2 = 16 + sub, e3 = 24 + sub;
    int sa0 = __shfl(sAlo, e0, 16), sa1 = __shfl(sAlo, e1, 16);
    int sa2 = __shfl(sAhi, e0, 16), sa3 = __shfl(sAhi, e1, 16);
    int sb0 = __shfl(sBlo, e0, 16), sb1 = __shfl(sBlo, e1, 16);
    int sb2 = __shfl(sBhi, e0, 16), sb3 = __shfl(sBhi, e1, 16);
    uint4 uA0 = make_uint4(0,0,0,0), uA1 = make_uint4(0,0,0,0);
    uint4 uA2 = make_uint4(0,0,0,0), uA3 = make_uint4(0,0,0,0);
    uint4 uB0 = make_uint4(0,0,0,0), uB1 = make_uint4(0,0,0,0);
    uint4 uB2 = make_uint4(0,0,0,0), uB3 = make_uint4(0,0,0,0);
    if (e0 < remA) uA0 = *(const uint4*)&feat[(size_t)sa0 * 16 + 8 * half];
    if (e1 < remA) uA1 = *(const uint4*)&feat[(size_t)sa1 * 16 + 8 * half];
    if (e2 < remA) uA2 = *(const uint4*)&feat[(size_t)sa2 * 16 + 8 * half];
    if (e3 < remA) uA3 = *(const uint4*)&feat[(size_t)sa3 * 16 + 8 * half];
    if (e0 < remB) uB0 = *(const uint4*)&feat[(size_t)sb0 * 16 + 8 * half];
    if (e1 < remB) uB1 = *(const uint4*)&feat[(size_t)sb1 * 16 + 8 * half];
    if (e2 < remB) uB2 = *(const uint4*)&feat[(size_t)sb2 * 16 + 8 * half];
    if (e3 < remB) uB3 = *(const uint4*)&feat[(size_t)sb3 * 16 + 8 * half];
    bfacc8(uA0, a); bfacc8(uA1, a); bfacc8(uA2, a); bfacc8(uA3, a);
    bfacc8(uB0, b); bfacc8(uB1, b); bfacc8(uB2, b); bfacc8(uB3, b);
}

// hist: per-block LDS hist over its chunk, then ~nbuck global atomics
// onto 64B-padded bucket totals.  No per-(bucket,block) counts array.
__global__ __launch_bounds__(TPB) void hist_kernel(const int* __restrict__ col,
                                                   int* __restrict__ btot,
                                                   int E, int nbuck) {
    __shared__ int hist[512];
    int t = threadIdx.x;
    hist[t] = 0; hist[t + TPB] = 0;
    __syncthreads();
    int e0 = blockIdx.x * CHUNK;
    int nE = min(CHUNK, E - e0);
    for (int i = t; i < nE; i += TPB)
        atomicAdd(&hist[col[e0 + i] >> BK_SHIFT], 1);         // LDS atomic
    __syncthreads();
    for (int i = t; i < nbuck; i += TPB)
        if (hist[i]) atomicAdd(&btot[i * CPAD], hist[i]);     // global atomic
}

// bscan: single block scans the <=512 bucket totals -> bstart (nbuck+1)
// and initializes the per-bucket allocation cursors.
__global__ __launch_bounds__(TPB) void bscan_kernel(const int* __restrict__ btot,
                                                    int* __restrict__ bstart,
                                                    int* __restrict__ cursor,
                                                    int nbuck, int E) {
    __shared__ int s[TPB];
    int t = threadIdx.x;
    int i0 = 2 * t, i1 = 2 * t + 1;
    int v0 = (i0 < nbuck) ? btot[i0 * CPAD] : 0;
    int v1 = (i1 < nbuck) ? btot[i1 * CPAD] : 0;
    int pv = v0 + v1;
    s[t] = pv; __syncthreads();
    for (int off = 1; off < TPB; off <<= 1) {
        int u = (t >= off) ? s[t - off] : 0;
        __syncthreads();
        s[t] += u;
        __syncthreads();
    }
    int exc = s[t] - pv;
    if (i0 < nbuck) { bstart[i0] = exc;      cursor[i0 * CPAD] = exc; }
    if (i1 < nbuck) { bstart[i1] = exc + v0; cursor[i1 * CPAD] = exc + v0; }
    if (t == 0) bstart[nbuck] = E;
}

// S1c ∥ gemm, block-interleaved 1:1.
// Scatter: local LDS hist, shfl-scan local offsets, atomicAdd per
//   nonempty bucket for the global base, LDS counting sort, bucket-
//   ordered coalesced writes of bucketed[pos]=(local_col<<18)|row.
// Gemm: 4 threads/node K-split, 2 nodes/thread (R17/R20).
__global__ __launch_bounds__(TPB) void s1c_gemm_kernel(
        const int* __restrict__ row, const int* __restrict__ col,
        int* __restrict__ cursor, int E, int nbuck,
        int* __restrict__ bucketed,
        const float* __restrict__ x, const float* __restrict__ W1,
        unsigned short* __restrict__ h1b, int N, int ns, int ng) {
    // unioned LDS: scatter 20544 B, gemm 10240 B
    __shared__ __align__(16) char sbuf[2048 + 2048 + CHUNK * 2 + 64];
    int* slhist = (int*)sbuf;                               // 512 ints
    int* sgd    = (int*)(sbuf + 2048);                      // 512 ints
    unsigned short* ssidx = (unsigned short*)(sbuf + 4096); // CHUNK ushort
    int* swtot  = (int*)(sbuf + 4096 + CHUNK * 2);          // 4 ints
    float* w1s  = (float*)sbuf;                             // gemm: 128x20 f32

    int b = (int)blockIdx.x, t = threadIdx.x;
    int M = min(ns, ng);
    int role, id;
    if (b < 2 * M) { role = b & 1; id = b >> 1; }
    else           { role = (ns > ng) ? 0 : 1; id = b - M; }

    if (role == 0) {                         // block-local counting sort
        int e0 = id * CHUNK;
        int nE = min(CHUNK, E - e0);
        int lane = t & 63, w = t >> 6;
        int bk0 = 2 * t, bk1 = 2 * t + 1;
        // pass A: local histogram of this chunk
        slhist[t] = 0; slhist[t + TPB] = 0;
        __syncthreads();
        for (int i = t; i < nE; i += TPB)
            atomicAdd(&slhist[col[e0 + i] >> BK_SHIFT], 1);    // LDS atomic
        __syncthreads();
        int c0 = slhist[bk0], c1 = slhist[bk1];
        int s = c0 + c1;
        // wave inclusive scan of s over 64 lanes (bin order == thread order)
        int v = s;
#pragma unroll
        for (int d = 1; d < 64; d <<= 1) {
            int u2 = __shfl_up(v, d, 64);
            if (lane >= d) v += u2;
        }
        if (lane == 63) swtot[w] = v;
        // global base per nonempty bucket via atomic allocation
        int gb0 = (bk0 < nbuck && c0 > 0) ? atomicAdd(&cursor[bk0 * CPAD], c0) : 0;
        int gb1 = (bk1 < nbuck && c1 > 0) ? atomicAdd(&cursor[bk1 * CPAD], c1) : 0;
        __syncthreads();
        int wbase = 0;
#pragma unroll
        for (int i = 0; i < 4; ++i) wbase += (i < w) ? swtot[i] : 0;
        int o0 = wbase + v - s;              // local exclusive start of bk0
        int o1 = o0 + c0;
        slhist[bk0] = o0; sgd[bk0] = gb0 - o0;
        slhist[bk1] = o1; sgd[bk1] = gb1 - o1;
        __syncthreads();
        // pass B: scatter chunk-local indices into sorted order
        for (int i = t; i < nE; i += TPB) {
            int c = col[e0 + i];
            int lp = atomicAdd(&slhist[c >> BK_SHIFT], 1);     // LDS atomic
            ssidx[lp] = (unsigned short)i;
        }
        __syncthreads();
        // pass C: write out in bucket order -> runs of consecutive addrs
        for (int j = t; j < nE; j += TPB) {
            int i = ssidx[j];
            int c = col[e0 + i];                               // L1/L2-hot
            int r = row[e0 + i];
            bucketed[sgd[c >> BK_SHIFT] + j] = ((c & (NPB - 1)) << 18) | r;
        }
        return;
    }
    // gemm: h1b[n] = bf16(x[n] @ W1).  4 threads/node K-split, 2 nodes/thread.
    for (int i = t; i < 128 * 16; i += TPB)
        w1s[(i >> 4) * W1S + (i & 15)] = W1[i];
    __syncthreads();
    int g = t >> 2, q = t & 3;
    int nA = id * 128 + g;
    int nB = nA + 64;
    int nAc = min(nA, N - 1), nBc = min(nB, N - 1);
    const float4* xA = (const float4*)(x + (size_t)nAc * 128);
    const float4* xB = (const float4*)(x + (size_t)nBc * 128);
    float4 xvA[8], xvB[8];
#pragma unroll
    for (int i = 0; i < 8; ++i) xvA[i] = xA[i * 4 + q];   // 16 loads in flight
#pragma unroll
    for (int i = 0; i < 8; ++i) xvB[i] = xB[i * 4 + q];
    float accA[16], accB[16];
#pragma unroll
    for (int k = 0; k < 16; ++k) { accA[k] = 0.f; accB[k] = 0.f; }
#pragma unroll
    for (int i = 0; i < 8; ++i) {
        float xjA[4] = {xvA[i].x, xvA[i].y, xvA[i].z, xvA[i].w};
        float xjB[4] = {xvB[i].x, xvB[i].y, xvB[i].z, xvB[i].w};
#pragma unroll
        for (int j = 0; j < 4; ++j) {
            int k = i * 16 + q * 4 + j;
            const float4* w4 = (const float4*)&w1s[k * W1S];
            float4 wa = w4[0], wb = w4[1], wc = w4[2], wd = w4[3];
            float xa = xjA[j], xb = xjB[j];
            accA[0]  = fmaf(xa, wa.x, accA[0]);  accA[1]  = fmaf(xa, wa.y, accA[1]);
            accA[2]  = fmaf(xa, wa.z, accA[2]);  accA[3]  = fmaf(xa, wa.w, accA[3]);
            accA[4]  = fmaf(xa, wb.x, accA[4]);  accA[5]  = fmaf(xa, wb.y, accA[5]);
            accA[6]  = fmaf(xa, wb.z, accA[6]);  accA[7]  = fmaf(xa, wb.w, accA[7]);
            accA[8]  = fmaf(xa, wc.x, accA[8]);  accA[9]  = fmaf(xa, wc.y, accA[9]);
            accA[10] = fmaf(xa, wc.z, accA[10]); accA[11] = fmaf(xa, wc.w, accA[11]);
            accA[12] = fmaf(xa, wd.x, accA[12]); accA[13] = fmaf(xa, wd.y, accA[13]);
            accA[14] = fmaf(xa, wd.z, accA[14]); accA[15] = fmaf(xa, wd.w, accA[15]);
            accB[0]  = fmaf(xb, wa.x, accB[0]);  accB[1]  = fmaf(xb, wa.y, accB[1]);
            accB[2]  = fmaf(xb, wa.z, accB[2]);  accB[3]  = fmaf(xb, wa.w, accB[3]);
            accB[4]  = fmaf(xb, wb.x, accB[4]);  accB[5]  = fmaf(xb, wb.y, accB[5]);
            accB[6]  = fmaf(xb, wb.z, accB[6]);  accB[7]  = fmaf(xb, wb.w, accB[7]);
            accB[8]  = fmaf(xb, wc.x, accB[8]);  accB[9]  = fmaf(xb, wc.y, accB[9]);
            accB[10] = fmaf(xb, wc.z, accB[10]); accB[11] = fmaf(xb, wc.w, accB[11]);
            accB[12] = fmaf(xb, wd.x, accB[12]); accB[13] = fmaf(xb, wd.y, accB[13]);
            accB[14] = fmaf(xb, wd.z, accB[14]); accB[15] = fmaf(xb, wd.w, accB[15]);
        }
    }
    // butterfly-reduce both accs across the 4 K-split lanes
#pragma unroll
    for (int d = 1; d < 4; d <<= 1) {
#pragma unroll
        for (int k = 0; k < 16; ++k) {
            accA[k] += __shfl_xor(accA[k], d, 4);
            accB[k] += __shfl_xor(accB[k], d, 4);
        }
    }
    if (nA < N) {                            // lane q stores feats 4q..4q+3
        unsigned int u0 = (unsigned int)f2bf(accA[4 * q]) |
                          ((unsigned int)f2bf(accA[4 * q + 1]) << 16);
        unsigned int u1 = (unsigned int)f2bf(accA[4 * q + 2]) |
                          ((unsigned int)f2bf(accA[4 * q + 3]) << 16);
        *(uint2*)&h1b[(size_t)nA * 16 + 4 * q] = make_uint2(u0, u1);
    }
    if (nB < N) {
        unsigned int u0 = (unsigned int)f2bf(accB[4 * q]) |
                          ((unsigned int)f2bf(accB[4 * q + 1]) << 16);
        unsigned int u1 = (unsigned int)f2bf(accB[4 * q + 2]) |
                          ((unsigned int)f2bf(accB[4 * q + 3]) << 16);
        *(uint2*)&h1b[(size_t)nB * 16 + 4 * q] = make_uint2(u0, u1);
    }
}

// S2: one block per 512-node bucket: counting sort, emit csr/offs/dinv,
// h1p = bf16(dinv * h1b).  Bucket range from bstart (R22).
__global__ __launch_bounds__(TPB) void sort_kernel(
        const int* __restrict__ bucketed, const int* __restrict__ bstart,
        int E, int nbuck,
        int* __restrict__ csr, int* __restrict__ offs, float* __restrict__ dinv,
        const unsigned short* __restrict__ h1b, unsigned short* __restrict__ h1p, int N) {
    __shared__ int lhist[NPB];
    __shared__ int part[TPB];
    __shared__ float sdinv[NPB];
    int bk = blockIdx.x, t = threadIdx.x;
    int n0 = bk << BK_SHIFT;
    int n1 = min(n0 + NPB, N);
    int e0 = bstart[bk];
    int e1 = bstart[bk + 1];

    lhist[t] = 0; lhist[t + TPB] = 0;
    __syncthreads();
    for (int i = e0 + t; i < e1; i += TPB)
        atomicAdd(&lhist[bucketed[i] >> 18], 1);               // LDS atomic
    __syncthreads();

    int base = t * 2;
    int c0 = lhist[base], c1 = lhist[base + 1];
    int s = c0 + c1;
    part[t] = s;
    __syncthreads();
    for (int off = 1; off < TPB; off <<= 1) {
        int v = (t >= off) ? part[t - off] : 0;
        __syncthreads();
        part[t] += v;
        __syncthreads();
    }
    int o0 = e0 + part[t] - s;
    int o1 = o0 + c0;
    lhist[base] = o0; lhist[base + 1] = o1;
    sdinv[base]     = rsqrtf((float)c0 + 1.0f);
    sdinv[base + 1] = rsqrtf((float)c1 + 1.0f);
    int n = n0 + base;
    if (n + 0 < N) { offs[n + 0] = o0; dinv[n + 0] = sdinv[base]; }
    if (n + 1 < N) { offs[n + 1] = o1; dinv[n + 1] = sdinv[base + 1]; }
    __syncthreads();

    for (int i = e0 + t; i < e1; i += TPB) {
        int v = bucketed[i];
        int pos = atomicAdd(&lhist[v >> 18], 1);               // LDS atomic
        csr[pos] = v & 0x3FFFF;
    }
    int nq = (n1 - n0) * 4;                  // one quad (4 feats) per i
    for (int i = t; i < nq; i += TPB) {
        float dv = sdinv[i >> 2];
        uint2 u = ((const uint2*)h1b)[(size_t)n0 * 4 + i];
        float f0 = bf2f((unsigned short)(u.x & 0xffff));
        float f1 = bf2f((unsigned short)(u.x >> 16));
        float f2 = bf2f((unsigned short)(u.y & 0xffff));
        float f3 = bf2f((unsigned short)(u.y >> 16));
        ((ushort4*)h1p)[(size_t)n0 * 4 + i] =
            make_ushort4(f2bf(f0 * dv), f2bf(f1 * dv), f2bf(f2 * dv), f2bf(f3 * dv));
    }
    if (bk == 0 && t == 0) offs[N] = E;
}

// gather1: 16 lanes per 2 nodes (R21 pair-pipelined).  Paired 32-edge
// rounds issue 4 csr + 8 feat loads before any accumulate; rare deg>32
// tails use single-node rounds.  8-lane tree reduce; lanes 0/1 finalize.
// h2p[c] = bf16( dinv[c]*relu( dinv[c]*(sum h1p[src] + h1p[c]) + b1 ) )
__global__ __launch_bounds__(TPB) void gather1_kernel(const int* __restrict__ csr,
                                                      const int* __restrict__ offs,
                                                      const unsigned short* __restrict__ h1p,
                                                      const float* __restrict__ dinv,
                                                      const float* __restrict__ b1,
                                                      unsigned short* __restrict__ h2p, int N) {
    int t = threadIdx.x;
    int grp = t >> 4, l = t & 15;
    int half = l & 1;                        // which 8-feature half-row
    int sub  = l >> 1;                       // edge slot 0..7
    int cA = blockIdx.x * 32 + grp * 2;
    int cB = cA + 1;
    if (cA >= N) return;
    bool hasB = cB < N;
    int pA = offs[cA], pA1 = offs[cA + 1];
    int pB = hasB ? offs[cB] : 0;
    int pB1 = hasB ? offs[cB + 1] : 0;
    float a[8], bb[8];
#pragma unroll
    for (int k = 0; k < 8; ++k) { a[k] = 0.f; bb[k] = 0.f; }
    while (pA < pA1 && pB < pB1) {           // paired rounds (usually 1)
        gather32_pair(csr, h1p, pA, pA1, pB, pB1, l, half, sub, a, bb);
        pA += 32; pB += 32;
    }
    while (pA < pA1) { gather32(csr, h1p, pA, pA1, l, half, sub, a); pA += 32; }
    while (pB < pB1) { gather32(csr, h1p, pB, pB1, l, half, sub, bb); pB += 32; }
#pragma unroll
    for (int d = 2; d < 16; d <<= 1) {
#pragma unroll
        for (int k = 0; k < 8; ++k) {
            a[k]  += __shfl_xor(a[k], d, 16);
            bb[k] += __shfl_xor(bb[k], d, 16);
        }
    }
    if (l < 2) {                             // l==half here
#pragma unroll
        for (int side = 0; side < 2; ++side) {
            int c = side ? cB : cA;
            float* av = side ? bb : a;
            if (side && !hasB) break;
            float dc = dinv[c];
            uint4 sv = *(const uint4*)&h1p[(size_t)c * 16 + 8 * l];
            float sf[8];
            bfunp8(sv, sf);
            unsigned int uo[4];
#pragma unroll
            for (int q = 0; q < 4; ++q) {
                float r0 = fmaf(dc, av[2 * q] + sf[2 * q], b1[8 * l + 2 * q]);
                float r1 = fmaf(dc, av[2 * q + 1] + sf[2 * q + 1], b1[8 * l + 2 * q + 1]);
                r0 = dc * fmaxf(r0, 0.f);
                r1 = dc * fmaxf(r1, 0.f);
                uo[q] = (unsigned int)f2bf(r0) | ((unsigned int)f2bf(r1) << 16);
            }
            *(uint4*)&h2p[(size_t)c * 16 + 8 * l] = make_uint4(uo[0], uo[1], uo[2], uo[3]);
        }
    }
}

// gather2f: fused gather2 + W2 matmul + sorted-batch pooling.  Block = 64 nodes.
// Phase 1: 16 groups x 16 lanes gather a2 rows — 2 pipelined PAIRS per
// group (R21) into LDS asT.
// Phase 2: wave w: 64 lanes = output dims, 16 nodes from asT, W2 slice in regs,
//          run-accumulate; uniform-batch blocks pool in LDS, flush 64 atomics.
__global__ __launch_bounds__(TPB) void gather2f_kernel(
        const int* __restrict__ csr, const int* __restrict__ offs,
        const unsigned short* __restrict__ h2p, const float* __restrict__ dinv,
        const float* __restrict__ W2, const float* __restrict__ b2,
        const int* __restrict__ batch, float* __restrict__ out, int N) {
    __shared__ float w2s[16 * 64];
    __shared__ float asT[64 * 17];
    __shared__ float pool[64];
    int t = threadIdx.x;
    for (int i = t; i < 16 * 64; i += TPB) w2s[i] = W2[i];
    if (t < 64) pool[t] = 0.f;

    int n0 = blockIdx.x * 64;
    int nLast = min(n0 + 63, N - 1);
    int g0 = batch[n0];
    bool uniform = (batch[nLast] == g0);     // batch sorted

    // phase 1: gather, 2 pipelined pairs per group
    int grp = t >> 4, l = t & 15;
    int half = l & 1, sub = l >> 1;
#pragma unroll 1
    for (int itp = 0; itp < 2; ++itp) {
        int mA = grp * 4 + itp * 2;
        int mB = mA + 1;
        int cA = n0 + mA, cB = n0 + mB;
        if (cA < N) {
            bool hasB = cB < N;
            int pA = offs[cA], pA1 = offs[cA + 1];
            int pB = hasB ? offs[cB] : 0;
            int pB1 = hasB ? offs[cB + 1] : 0;
            float a[8], bb[8];
#pragma unroll
            for (int k = 0; k < 8; ++k) { a[k] = 0.f; bb[k] = 0.f; }
            while (pA < pA1 && pB < pB1) {
                gather32_pair(csr, h2p, pA, pA1, pB, pB1, l, half, sub, a, bb);
                pA += 32; pB += 32;
            }
            while (pA < pA1) { gather32(csr, h2p, pA, pA1, l, half, sub, a); pA += 32; }
            while (pB < pB1) { gather32(csr, h2p, pB, pB1, l, half, sub, bb); pB += 32; }
#pragma unroll
            for (int d = 2; d < 16; d <<= 1) {
#pragma unroll
                for (int k = 0; k < 8; ++k) {
                    a[k]  += __shfl_xor(a[k], d, 16);
                    bb[k] += __shfl_xor(bb[k], d, 16);
                }
            }
            if (l < 2) {
#pragma unroll
                for (int side = 0; side < 2; ++side) {
                    int c = side ? cB : cA;
                    int m = side ? mB : mA;
                    float* av = side ? bb : a;
                    if (side && !hasB) break;
                    float dc = dinv[c];
                    uint4 sv = *(const uint4*)&h2p[(size_t)c * 16 + 8 * l];
                    float sf[8];
                    bfunp8(sv, sf);
#pragma unroll
                    for (int k = 0; k < 8; ++k)
                        asT[m * 17 + 8 * l + k] = dc * (av[k] + sf[k]);
                }
            }
        }
    }
    __syncthreads();

    // phase 2: wave w covers nodes n0+16w .. n0+16w+15
    int wave = t >> 6, j = t & 63;
    float w2reg[16];
#pragma unroll
    for (int kx = 0; kx < 16; ++kx) w2reg[kx] = w2s[kx * 64 + j];
    float b2j = b2[j];
    float val = 0.f;
    int g_cur = -1;
#pragma unroll 1
    for (int mi = 0; mi < 16; ++mi) {
        int m = wave * 16 + mi;
        int c = n0 + m;
        if (c >= N) break;
        const float* ar = &asT[m * 17];
        float y = b2j;
#pragma unroll
        for (int kx = 0; kx < 16; ++kx) y = fmaf(ar[kx], w2reg[kx], y);
        if (uniform) {
            val += y;
        } else {
            int g = batch[c];
            if (g != g_cur) {
                if (g_cur >= 0) atomicAdd(&out[(size_t)g_cur * 64 + j], val);
                val = 0.f;
                g_cur = g;
            }
            val += y;
        }
    }
    if (uniform) {
        atomicAdd(&pool[j], val);            // LDS, 4-way per address
        __syncthreads();
        if (t < 64) atomicAdd(&out[(size_t)g0 * 64 + t], pool[t]);
    } else {
        if (g_cur >= 0) atomicAdd(&out[(size_t)g_cur * 64 + j], val);
    }
}

static inline size_t align64(size_t v) { return (v + 63) & ~(size_t)63; }

extern "C" void kernel_launch(void* const* d_in, const int* in_sizes, int n_in,
                              void* d_out, int out_size, void* d_ws, size_t ws_size,
                              hipStream_t stream) {
    const float* x     = (const float*)d_in[0];
    const int*   ei    = (const int*)d_in[1];
    const int*   batch = (const int*)d_in[2];
    const float* W1    = (const float*)d_in[3];
    const float* b1    = (const float*)d_in[4];
    const float* W2    = (const float*)d_in[5];
    const float* b2    = (const float*)d_in[6];

    const int N = in_sizes[0] / 128;
    const int E = in_sizes[1] / 2;
    const int* row = ei;        // edge_index[0]
    const int* col = ei + E;    // edge_index[1]

    const int NBLK  = (E + CHUNK - 1) / CHUNK;       // 391 scatter/hist blocks
    const int NBUCK = (N + NPB - 1) / NPB;           // 391 (<=512)
    const int NBG   = (N + 127) / 128;               // 1563 gemm blocks

    char* p = (char*)d_ws;
    int*            btot     = (int*)p;            p += align64(512 * CPAD * 4);
    int*            cursor   = (int*)p;            p += align64(512 * CPAD * 4);
    int*            bstart   = (int*)p;            p += align64(520 * 4);
    int*            bucketed = (int*)p;            p += align64((size_t)E * 4);
    int*            csr      = (int*)p;            p += align64((size_t)E * 4);
    int*            offs     = (int*)p;            p += align64((size_t)(N + 1) * 4);
    float*          dinv     = (float*)p;          p += align64((size_t)N * 4);
    unsigned short* h1b      = (unsigned short*)p; p += align64((size_t)N * 16 * 2);
    unsigned short* h1p      = (unsigned short*)p; p += align64((size_t)N * 16 * 2);
    unsigned short* h2p      = (unsigned short*)p; p += align64((size_t)N * 16 * 2);
    float*          out      = (float*)d_out;

    hipMemsetAsync(out, 0, (size_t)out_size * sizeof(float), stream);
    hipMemsetAsync(btot, 0, 512 * CPAD * 4, stream);

    hist_kernel<<<NBLK, TPB, 0, stream>>>(col, btot, E, NBUCK);
    bscan_kernel<<<1, TPB, 0, stream>>>(btot, bstart, cursor, NBUCK, E);
    s1c_gemm_kernel<<<NBLK + NBG, TPB, 0, stream>>>(row, col, cursor, E, NBUCK,
                                                    bucketed, x, W1, h1b, N,
                                                    NBLK, NBG);
    sort_kernel<<<NBUCK, TPB, 0, stream>>>(bucketed, bstart, E, NBUCK,
                                           csr, offs, dinv, h1b, h1p, N);
    gather1_kernel<<<(N + 31) / 32, TPB, 0, stream>>>(csr, offs, h1p, dinv, b1, h2p, N);
    gather2f_kernel<<<(N + 63) / 64, TPB, 0, stream>>>(csr, offs, h2p, dinv,
                                                       W2, b2, batch, out, N);
}